// Round 6
// baseline (379.312 us; speedup 1.0000x reference)
//
#include <hip/hip_runtime.h>
#include <math.h>

#define HW 65536

typedef float f32x4 __attribute__((ext_vector_type(4)));
typedef short bf16x8 __attribute__((ext_vector_type(8)));
typedef short bf16x4 __attribute__((ext_vector_type(4)));

// ---- ws layout (byte offsets) ----
static constexpr size_t OFF_A0    = 0;
static constexpr size_t OFF_SP    = 100663296;
static constexpr size_t OFF_QKT   = 150994944;
static constexpr size_t OFF_VPL   = 251658240;
static constexpr size_t OFF_PT    = 301989888;  // 1,048,576 B
static constexpr size_t OFF_NORMS = 303038464;  // 16,384 B
static constexpr size_t OFF_WQ    = 303054848;  // 221,184 B
static constexpr size_t OFF_WP    = 303276032;  // 73,728 B   (end 303,349,760)

__device__ inline float b2f(unsigned short u) { union { unsigned u; float f; } v; v.u = ((unsigned)u) << 16; return v.f; }
__device__ inline unsigned short f2b(float f) {
    union { float f; unsigned u; } v; v.f = f;
    return (unsigned short)((v.u + 0x7fffu + ((v.u >> 16) & 1u)) >> 16);
}

// ---------------- convert weights to bf16
__global__ __launch_bounds__(256) void conv_w(const float* __restrict__ wq, const float* __restrict__ wp,
                                              unsigned short* __restrict__ wqb, unsigned short* __restrict__ wpb)
{
    int t = blockIdx.x * 256 + threadIdx.x;
    int stride = gridDim.x * 256;
    for (int i = t; i < 576 * 192; i += stride) wqb[i] = f2b(wq[i]);
    for (int i = t; i < 192 * 192; i += stride) wpb[i] = f2b(wp[i]);
}

// ---------------- MFMA GEMM v4: 64-px tile staged to LDS in [ch/4][px/16][4][16]
// subtiles; B fragments gathered via ds_read_b64_tr_b16 (HW transpose read).
// MODE 0: qkv (src f32 planar x, out bf16 planar). MODE 1: proj (src bf16 planar, out f32).
template <int MODE>
__global__ __launch_bounds__(256) void gemm_pm4(const unsigned short* __restrict__ Aw,
                                                const void* __restrict__ Bsrc,
                                                unsigned short* __restrict__ outb,
                                                float* __restrict__ outf, int Mtiles)
{
    __shared__ __align__(1024) unsigned short Bs[12288];   // 48 quads * [4 pxtile][4 ch][16 px]
    int tid = threadIdx.x;
    int w = tid >> 6, lane = tid & 63, lg = lane >> 4, li = lane & 15;
    int wm = w >> 1, wn = w & 1;
    const int b = (int)(blockIdx.x >> 10);
    const long px0 = (long)(blockIdx.x & 1023) * 64;

    if (MODE == 0) {
        const float* X = (const float*)Bsrc;
#pragma unroll
        for (int it = 0; it < 12; ++it) {
            int t = it * 256 + tid;                       // 3072 = 192ch * 16 pxquads
            int ch  = (t & 3) + 4 * ((t >> 5) % 48);
            int pxq = ((t >> 2) & 7) + 8 * ((t >> 5) / 48);
            float4 v = *(const float4*)(X + ((long)(b * 192 + ch)) * HW + px0 + pxq * 4);
            bf16x4 pv;
            pv[0] = (short)f2b(v.x); pv[1] = (short)f2b(v.y);
            pv[2] = (short)f2b(v.z); pv[3] = (short)f2b(v.w);
            int px = pxq * 4;
            *(bf16x4*)&Bs[(ch >> 2) * 256 + (px >> 4) * 64 + (ch & 3) * 16 + (px & 15)] = pv;
        }
    } else {
        const unsigned short* X = (const unsigned short*)Bsrc;
#pragma unroll
        for (int it = 0; it < 6; ++it) {
            int t = it * 256 + tid;                       // 1536 = 192ch * 8 pxocts
            int ch  = (t & 3) + 4 * ((t >> 4) % 48);
            int pxo = ((t >> 2) & 3) + 4 * ((t >> 4) / 48);
            bf16x8 v = *(const bf16x8*)(X + ((long)(b * 192 + ch)) * HW + px0 + pxo * 8);
            int px = pxo * 8;
            *(bf16x8*)&Bs[(ch >> 2) * 256 + (px >> 4) * 64 + (ch & 3) * 16 + (px & 15)] = v;
        }
    }
    __syncthreads();

    // HW transpose gather: window for 16-lane group lg at vb base covers
    // [4 ch][16 px] row-major; lane gets px col (l&15), elems j = ch rows.
    unsigned vb = (unsigned)(size_t)&Bs[(lane & 15) * 4 + (lane >> 4) * 512 + wn * 128];
    bf16x4 tr[2][6][2];
#define TRR(FB,KS,G,OFF) asm volatile("ds_read_b64_tr_b16 %0, %1 offset:" OFF \
        : "=v"(tr[FB][KS][G]) : "v"(vb))
    TRR(0,0,0,"0");     TRR(0,0,1,"512");
    TRR(0,1,0,"4096");  TRR(0,1,1,"4608");
    TRR(0,2,0,"8192");  TRR(0,2,1,"8704");
    TRR(0,3,0,"12288"); TRR(0,3,1,"12800");
    TRR(0,4,0,"16384"); TRR(0,4,1,"16896");
    TRR(0,5,0,"20480"); TRR(0,5,1,"20992");
    TRR(1,0,0,"128");   TRR(1,0,1,"640");
    TRR(1,1,0,"4224");  TRR(1,1,1,"4736");
    TRR(1,2,0,"8320");  TRR(1,2,1,"8832");
    TRR(1,3,0,"12416"); TRR(1,3,1,"12928");
    TRR(1,4,0,"16512"); TRR(1,4,1,"17024");
    TRR(1,5,0,"20608"); TRR(1,5,1,"21120");
#undef TRR
    asm volatile("s_waitcnt lgkmcnt(0)" ::: "memory");
    __builtin_amdgcn_sched_barrier(0);

    bf16x8 Bf[2][6];
#pragma unroll
    for (int fb = 0; fb < 2; ++fb)
#pragma unroll
        for (int ks = 0; ks < 6; ++ks)
            Bf[fb][ks] = __builtin_shufflevector(tr[fb][ks][0], tr[fb][ks][1], 0, 1, 2, 3, 4, 5, 6, 7);

    const int pxl = (int)px0 + wn * 32;
    const int Mtot = Mtiles * 64;

    for (int mt = 0; mt < Mtiles; ++mt) {
        int oc0 = mt * 64;
        const unsigned short* ab = Aw + (long)(oc0 + wm * 32 + li) * 192 + lg * 8;
        f32x4 acc[2][2];
#pragma unroll
        for (int i = 0; i < 2; ++i)
#pragma unroll
            for (int j = 0; j < 2; ++j) acc[i][j] = (f32x4){0.f, 0.f, 0.f, 0.f};
#pragma unroll
        for (int ks = 0; ks < 6; ++ks) {
            bf16x8 a0 = *(const bf16x8*)(ab + ks * 32);
            bf16x8 a1 = *(const bf16x8*)(ab + 16 * 192 + ks * 32);
            acc[0][0] = __builtin_amdgcn_mfma_f32_16x16x32_bf16(a0, Bf[0][ks], acc[0][0], 0, 0, 0);
            acc[0][1] = __builtin_amdgcn_mfma_f32_16x16x32_bf16(a0, Bf[1][ks], acc[0][1], 0, 0, 0);
            acc[1][0] = __builtin_amdgcn_mfma_f32_16x16x32_bf16(a1, Bf[0][ks], acc[1][0], 0, 0, 0);
            acc[1][1] = __builtin_amdgcn_mfma_f32_16x16x32_bf16(a1, Bf[1][ks], acc[1][1], 0, 0, 0);
        }
#pragma unroll
        for (int fa = 0; fa < 2; ++fa) {
            int m = oc0 + wm * 32 + fa * 16 + lg * 4;
#pragma unroll
            for (int fb = 0; fb < 2; ++fb) {
                int px = pxl + fb * 16 + li;
                long base = ((long)b * Mtot + m) * HW + px;
#pragma unroll
                for (int ii = 0; ii < 4; ++ii) {
                    if (MODE == 1) outf[base + (long)ii * HW] = acc[fa][fb][ii];
                    else           outb[base + (long)ii * HW] = f2b(acc[fa][fb][ii]);
                }
            }
        }
    }
}

// ---------------- depthwise 3x3 SAME v2: 32-row strips, aligned b64 LDS reads,
// 4x x 8y outputs/thread; q/k written directly in qkT layout, v planar.
__global__ __launch_bounds__(256) void dwconv2(const unsigned short* __restrict__ in,
                                               const float* __restrict__ wdw,
                                               unsigned short* __restrict__ qkT,
                                               unsigned short* __restrict__ vpl)
{
    __shared__ unsigned short Ls[34 * 272];
    int tid = threadIdx.x;
    int zp = blockIdx.y;
    int b = zp / 576, ch3 = zp % 576;
    int y0 = blockIdx.x * 32;
    const unsigned short* ip = in + (long)zp * HW;
    float w9[9];
#pragma unroll
    for (int t = 0; t < 9; ++t) w9[t] = wdw[ch3 * 9 + t];

    const bf16x8 z8 = (bf16x8){0, 0, 0, 0, 0, 0, 0, 0};
    if (tid < 34)               *(bf16x8*)&Ls[tid * 272] = z8;
    else if (tid < 68)          *(bf16x8*)&Ls[(tid - 34) * 272 + 264] = z8;
#pragma unroll
    for (int it = 0; it < 5; ++it) {
        int task = it * 256 + tid;
        if (task < 1088) {
            int r = task >> 5, seg = task & 31;
            int gy = y0 - 1 + r;
            bf16x8 v = z8;
            if (gy >= 0 && gy < 256) v = *(const bf16x8*)(ip + gy * 256 + seg * 8);
            *(bf16x8*)&Ls[r * 272 + 8 + seg * 8] = v;
        }
    }
    __syncthreads();

    int xg = tid & 63, yg = tid >> 6;
    int x0 = xg * 4;
    float acc[8][4];
#pragma unroll
    for (int yy = 0; yy < 8; ++yy)
#pragma unroll
        for (int xi = 0; xi < 4; ++xi) acc[yy][xi] = 0.f;

#pragma unroll
    for (int rr = 0; rr < 10; ++rr) {
        const unsigned short* lp = &Ls[(yg * 8 + rr) * 272 + 8 + x0];
        bf16x4 A  = *(const bf16x4*)(lp - 4);
        bf16x4 Bv = *(const bf16x4*)(lp);
        bf16x4 Cv = *(const bf16x4*)(lp + 4);
        float f[6] = { b2f((unsigned short)A[3]),  b2f((unsigned short)Bv[0]),
                       b2f((unsigned short)Bv[1]), b2f((unsigned short)Bv[2]),
                       b2f((unsigned short)Bv[3]), b2f((unsigned short)Cv[0]) };
#pragma unroll
        for (int dy = 0; dy < 3; ++dy) {
            int yy = rr - dy;
            if (yy >= 0 && yy < 8) {
#pragma unroll
                for (int dx = 0; dx < 3; ++dx)
#pragma unroll
                    for (int xi = 0; xi < 4; ++xi)
                        acc[yy][xi] = fmaf(w9[dy * 3 + dx], f[dx + xi], acc[yy][xi]);
            }
        }
    }

    if (ch3 < 384) {
        int isk = ch3 >= 192 ? 1 : 0;
        int chq = ch3 - isk * 192;
        int hh = chq / 48, cc = chq % 48;
        long zbase = (long)(b * 8 + isk * 4 + hh) * 3145728L + (long)cc * 256 + y0 + yg * 8;
#pragma unroll
        for (int xi = 0; xi < 4; ++xi) {
            bf16x8 pv;
#pragma unroll
            for (int yy = 0; yy < 8; ++yy) pv[yy] = (short)f2b(acc[yy][xi]);
            *(bf16x8*)(qkT + zbase + (long)(x0 + xi) * 12288) = pv;
        }
    } else {
        unsigned short* ob = vpl + (long)(b * 192 + ch3 - 384) * HW + (long)(y0 + yg * 8) * 256 + x0;
#pragma unroll
        for (int yy = 0; yy < 8; ++yy) {
            bf16x4 pv;
#pragma unroll
            for (int xi = 0; xi < 4; ++xi) pv[xi] = (short)f2b(acc[yy][xi]);
            *(bf16x4*)(ob + yy * 256) = pv;
        }
    }
}

// ---------------- column norms: 1/max(||row of qkT||,eps). grid (256, 16)
__global__ __launch_bounds__(256) void norms_k(const unsigned short* __restrict__ qkT, float* __restrict__ norms)
{
    int i = blockIdx.x, z = blockIdx.y;
    const unsigned short* p = qkT + ((long)z * 256 + i) * 12288 + threadIdx.x * 8;
    float s = 0.f;
#pragma unroll
    for (int it = 0; it < 6; ++it) {
        bf16x8 v = *(const bf16x8*)(p + it * 2048);
#pragma unroll
        for (int e = 0; e < 8; ++e) { float f = b2f((unsigned short)v[e]); s = fmaf(f, f, s); }
    }
    for (int off = 32; off > 0; off >>= 1) s += __shfl_down(s, off, 64);
    __shared__ float r4[4];
    if ((threadIdx.x & 63) == 0) r4[threadIdx.x >> 6] = s;
    __syncthreads();
    if (threadIdx.x == 0) {
        float t = r4[0] + r4[1] + r4[2] + r4[3];
        norms[z * 256 + i] = 1.0f / fmaxf(sqrtf(t), 1e-12f);
    }
}

// ---------------- attn: Sp[sk][bh][i][j] partial of Q^T K. grid (2,2,128), K-chunk 768.
__global__ __launch_bounds__(256) void attn_qk(const unsigned short* __restrict__ qkT, float* __restrict__ Sp)
{
    __shared__ unsigned short Qs[128 * 40];
    __shared__ unsigned short Ks[128 * 40];
    int tid = threadIdx.x;
    int z = blockIdx.z; int bh = z >> 4, sk = z & 15; int b = bh >> 2, h = bh & 3;
    const unsigned short* qT = qkT + (long)(b * 8 + h) * 3145728;
    const unsigned short* kT = qkT + (long)(b * 8 + 4 + h) * 3145728;
    int i0 = blockIdx.x * 128, j0 = blockIdx.y * 128;
    int w = tid >> 6, lane = tid & 63, lg = lane >> 4, li = lane & 15;
    int wm = w >> 1, wn = w & 1;
    int srow = tid >> 2, sseg = (tid & 3) * 8;
    long qoff = (long)(i0 + srow) * 12288 + sk * 768 + sseg;
    long koff = (long)(j0 + srow) * 12288 + sk * 768 + sseg;

    f32x4 acc[4][4];
#pragma unroll
    for (int i = 0; i < 4; ++i)
#pragma unroll
        for (int j = 0; j < 4; ++j) acc[i][j] = (f32x4){0.f, 0.f, 0.f, 0.f};

    bf16x8 qr0 = *(const bf16x8*)(qT + qoff);
    bf16x8 qr1 = *(const bf16x8*)(qT + qoff + (long)64 * 12288);
    bf16x8 kr0 = *(const bf16x8*)(kT + koff);
    bf16x8 kr1 = *(const bf16x8*)(kT + koff + (long)64 * 12288);

#pragma unroll 1
    for (int ks = 0; ks < 24; ++ks) {
        *(bf16x8*)&Qs[srow * 40 + sseg] = qr0;
        *(bf16x8*)&Qs[(64 + srow) * 40 + sseg] = qr1;
        *(bf16x8*)&Ks[srow * 40 + sseg] = kr0;
        *(bf16x8*)&Ks[(64 + srow) * 40 + sseg] = kr1;
        if (ks < 23) {
            long o = (long)(ks + 1) * 32;
            qr0 = *(const bf16x8*)(qT + qoff + o);
            qr1 = *(const bf16x8*)(qT + qoff + (long)64 * 12288 + o);
            kr0 = *(const bf16x8*)(kT + koff + o);
            kr1 = *(const bf16x8*)(kT + koff + (long)64 * 12288 + o);
        }
        __syncthreads();
        bf16x8 af[4], bfr[4];
#pragma unroll
        for (int fa = 0; fa < 4; ++fa)
            af[fa] = *(const bf16x8*)&Qs[(wm * 64 + fa * 16 + li) * 40 + lg * 8];
#pragma unroll
        for (int fb = 0; fb < 4; ++fb)
            bfr[fb] = *(const bf16x8*)&Ks[(wn * 64 + fb * 16 + li) * 40 + lg * 8];
#pragma unroll
        for (int fa = 0; fa < 4; ++fa)
#pragma unroll
            for (int fb = 0; fb < 4; ++fb)
                acc[fa][fb] = __builtin_amdgcn_mfma_f32_16x16x32_bf16(af[fa], bfr[fb], acc[fa][fb], 0, 0, 0);
        __syncthreads();
    }

    float* op = Sp + ((long)(sk * 8 + bh) << 16);
#pragma unroll
    for (int fa = 0; fa < 4; ++fa) {
        int i = i0 + wm * 64 + fa * 16 + lg * 4;
#pragma unroll
        for (int fb = 0; fb < 4; ++fb) {
            int j = j0 + wn * 64 + fb * 16 + li;
#pragma unroll
            for (int ii = 0; ii < 4; ++ii)
                op[(long)(i + ii) * 256 + j] = acc[fa][fb][ii];
        }
    }
}

// ---------------- softmax over i with scaling; writes Pt in vattn B-fragment layout.
__global__ __launch_bounds__(256) void softmax_k(const float* __restrict__ Sp, const float* __restrict__ norms,
                                                 const float* __restrict__ temp, unsigned short* __restrict__ Pt)
{
    __shared__ float Sd[256 * 9];
    __shared__ float red[32 * 9];
    int tid = threadIdx.x;
    int g = blockIdx.x; int bh = g >> 5, jq = g & 31; int b = bh >> 2, h = bh & 3;
    int jl = tid & 7, iq = tid >> 3;
    int j = jq * 8 + jl;
    const float* nq = norms + (b * 8 + h) * 256;
    float invkj = norms[(b * 8 + 4 + h) * 256 + j] * temp[h];
    const float* sp = Sp + (long)bh * HW + j;

    float m = -1e30f;
#pragma unroll
    for (int ii = 0; ii < 8; ++ii) {
        int i = iq * 8 + ii;
        float s = 0.f;
#pragma unroll
        for (int sk = 0; sk < 16; ++sk) s += sp[((long)(sk * 8) << 16) + i * 256];
        float v = s * nq[i] * invkj;
        Sd[i * 9 + jl] = v;
        m = fmaxf(m, v);
    }
    red[iq * 9 + jl] = m;
    __syncthreads();
    m = -1e30f;
#pragma unroll
    for (int s2 = 0; s2 < 32; ++s2) m = fmaxf(m, red[s2 * 9 + jl]);
    __syncthreads();
    float sum = 0.f;
#pragma unroll
    for (int ii = 0; ii < 8; ++ii) sum += __expf(Sd[(iq * 8 + ii) * 9 + jl] - m);
    red[iq * 9 + jl] = sum;
    __syncthreads();
    sum = 0.f;
#pragma unroll
    for (int s2 = 0; s2 < 32; ++s2) sum += red[s2 * 9 + jl];
    float rs = 1.0f / sum;

    int fb = jq >> 1, li2 = (jq & 1) * 8 + jl;
    int ks = iq >> 2, lg = iq & 3;
    unsigned short* pt = Pt + (long)bh * HW + (long)((fb * 8 + ks) * 64 + lg * 16 + li2) * 8;
    bf16x8 pv;
#pragma unroll
    for (int ii = 0; ii < 8; ++ii)
        pv[ii] = (short)f2b(__expf(Sd[(iq * 8 + ii) * 9 + jl] - m) * rs);
    *(bf16x8*)pt = pv;
}

// ---------------- vattn: P in fragment layout (coalesced 1KB loads), no LDS. grid (192, 8)
__global__ __launch_bounds__(256) void vattn(const unsigned short* __restrict__ vpl,
                                             const unsigned short* __restrict__ Pt,
                                             unsigned short* __restrict__ vout)
{
    int tid = threadIdx.x;
    int w = tid >> 6, lane = tid & 63, lg = lane >> 4, li = lane & 15;
    int wm = w >> 1, wn = w & 1;
    int m0 = blockIdx.x * 64 + wm * 32;
    int bh = blockIdx.y; int b = bh >> 2, h = bh & 3;
    const unsigned short* V = vpl + (long)(b * 192 + h * 48) * HW;
    const unsigned short* P = Pt + (long)bh * HW + wn * 32768 + lane * 8;

    f32x4 acc[2][8];
#pragma unroll
    for (int i = 0; i < 2; ++i)
#pragma unroll
        for (int j = 0; j < 8; ++j) acc[i][j] = (f32x4){0.f, 0.f, 0.f, 0.f};

#pragma unroll 2
    for (int ks = 0; ks < 8; ++ks) {
        bf16x8 a0 = *(const bf16x8*)(V + (long)(m0 + li) * 256 + ks * 32 + lg * 8);
        bf16x8 a1 = *(const bf16x8*)(V + (long)(m0 + 16 + li) * 256 + ks * 32 + lg * 8);
#pragma unroll
        for (int fb2 = 0; fb2 < 8; ++fb2) {
            bf16x8 bb = *(const bf16x8*)(P + (fb2 * 8 + ks) * 512);
            acc[0][fb2] = __builtin_amdgcn_mfma_f32_16x16x32_bf16(a0, bb, acc[0][fb2], 0, 0, 0);
            acc[1][fb2] = __builtin_amdgcn_mfma_f32_16x16x32_bf16(a1, bb, acc[1][fb2], 0, 0, 0);
        }
    }
    unsigned short* ob = vout + (long)(b * 192 + h * 48) * HW;
#pragma unroll
    for (int fa = 0; fa < 2; ++fa) {
#pragma unroll
        for (int fb2 = 0; fb2 < 8; ++fb2) {
            int j = (wn * 8 + fb2) * 16 + li;
#pragma unroll
            for (int ii = 0; ii < 4; ++ii) {
                int m = m0 + fa * 16 + lg * 4 + ii;
                ob[((long)(m >> 8) << 16) + ((m & 255) << 8) + j] = f2b(acc[fa][fb2][ii]);
            }
        }
    }
}

extern "C" void kernel_launch(void* const* d_in, const int* in_sizes, int n_in,
                              void* d_out, int out_size, void* d_ws, size_t ws_size,
                              hipStream_t stream)
{
    (void)in_sizes; (void)n_in; (void)out_size; (void)ws_size;
    const float* x      = (const float*)d_in[0];
    const float* w_qkv  = (const float*)d_in[1];
    const float* w_dw   = (const float*)d_in[2];
    const float* w_proj = (const float*)d_in[3];
    const float* temp   = (const float*)d_in[4];
    float* out = (float*)d_out;
    char* ws = (char*)d_ws;

    unsigned short* qkv_pre = (unsigned short*)(ws + OFF_A0);
    float*          Sp      = (float*)(ws + OFF_SP);
    unsigned short* vout    = (unsigned short*)(ws + OFF_A0);
    unsigned short* qkT     = (unsigned short*)(ws + OFF_QKT);
    unsigned short* vpl     = (unsigned short*)(ws + OFF_VPL);
    unsigned short* Pt      = (unsigned short*)(ws + OFF_PT);
    float*          norms   = (float*)(ws + OFF_NORMS);
    unsigned short* wqb     = (unsigned short*)(ws + OFF_WQ);
    unsigned short* wpb     = (unsigned short*)(ws + OFF_WP);

    conv_w<<<64, 256, 0, stream>>>(w_qkv, w_proj, wqb, wpb);
    gemm_pm4<0><<<2048, 256, 0, stream>>>(wqb, (const void*)x, qkv_pre, nullptr, 9);
    dwconv2<<<dim3(8, 1152), 256, 0, stream>>>(qkv_pre, w_dw, qkT, vpl);
    norms_k<<<dim3(256, 16), 256, 0, stream>>>(qkT, norms);
    attn_qk<<<dim3(2, 2, 128), 256, 0, stream>>>(qkT, Sp);
    softmax_k<<<256, 256, 0, stream>>>(Sp, norms, temp, Pt);
    vattn<<<dim3(192, 8), 256, 0, stream>>>(vpl, Pt, vout);
    gemm_pm4<1><<<2048, 256, 0, stream>>>(wpb, (const void*)vout, nullptr, out, 3);
}

// Round 7
// 332.891 us; speedup vs baseline: 1.1394x; 1.1394x over previous
//
#include <hip/hip_runtime.h>
#include <math.h>

#define HW 65536

typedef float f32x4 __attribute__((ext_vector_type(4)));
typedef short bf16x8 __attribute__((ext_vector_type(8)));
typedef short bf16x4 __attribute__((ext_vector_type(4)));

// ---- ws layout (byte offsets) ----
static constexpr size_t OFF_A0    = 0;
static constexpr size_t OFF_SP    = 100663296;
static constexpr size_t OFF_QKT   = 150994944;
static constexpr size_t OFF_VPL   = 251658240;
static constexpr size_t OFF_PT    = 301989888;  // 1,048,576 B
static constexpr size_t OFF_NORMS = 303038464;  // 16,384 B
static constexpr size_t OFF_WQ    = 303054848;  // 221,184 B
static constexpr size_t OFF_WP    = 303276032;  // 73,728 B   (end 303,349,760)

__device__ inline float b2f(unsigned short u) { union { unsigned u; float f; } v; v.u = ((unsigned)u) << 16; return v.f; }
__device__ inline unsigned short f2b(float f) {
    union { float f; unsigned u; } v; v.f = f;
    return (unsigned short)((v.u + 0x7fffu + ((v.u >> 16) & 1u)) >> 16);
}

// ---------------- convert weights to bf16
__global__ __launch_bounds__(256) void conv_w(const float* __restrict__ wq, const float* __restrict__ wp,
                                              unsigned short* __restrict__ wqb, unsigned short* __restrict__ wpb)
{
    int t = blockIdx.x * 256 + threadIdx.x;
    int stride = gridDim.x * 256;
    for (int i = t; i < 576 * 192; i += stride) wqb[i] = f2b(wq[i]);
    for (int i = t; i < 192 * 192; i += stride) wpb[i] = f2b(wp[i]);
}

// ---------------- MFMA GEMM v5: pm3 structure (128-px tile, LDS [192][130] staging,
// register-hoisted B fragments) + LDS-bounce epilogue producing contiguous b128 stores.
// MODE 0: qkv (src f32 planar x, out bf16 planar). MODE 1: proj (src bf16 planar, out f32).
template <int MODE>
__global__ __launch_bounds__(256) void gemm_pm5(const unsigned short* __restrict__ Aw,
                                                const void* __restrict__ Bsrc,
                                                unsigned short* __restrict__ outb,
                                                float* __restrict__ outf, int Mtiles)
{
    __shared__ unsigned short Bs[192 * 130];   // 49,920 B; overlaid as epilogue scratch later
    int tid = threadIdx.x;
    int w = tid >> 6, lane = tid & 63, lg = lane >> 4, li = lane & 15;
    int wm = w >> 1, wn = w & 1;
    const int b = (int)(blockIdx.x >> 9);
    const long px0 = (long)(blockIdx.x & 511) * 128;

    if (MODE == 0) {
        const float* X = (const float*)Bsrc;
#pragma unroll
        for (int it = 0; it < 24; ++it) {
            int task = it * 256 + tid;               // 6144 = 192ch * 32seg
            int ch = task >> 5, seg = task & 31;
            float4 v = *(const float4*)(X + ((long)(b * 192 + ch)) * HW + px0 + seg * 4);
            unsigned* d32 = (unsigned*)&Bs[ch * 130 + seg * 4];
            d32[0] = (unsigned)f2b(v.x) | ((unsigned)f2b(v.y) << 16);
            d32[1] = (unsigned)f2b(v.z) | ((unsigned)f2b(v.w) << 16);
        }
    } else {
        const unsigned short* X = (const unsigned short*)Bsrc;
#pragma unroll
        for (int it = 0; it < 12; ++it) {
            int task = it * 256 + tid;               // 3072 = 192ch * 16seg
            int ch = task >> 4, seg = task & 15;
            bf16x8 v = *(const bf16x8*)(X + ((long)(b * 192 + ch)) * HW + px0 + seg * 8);
            unsigned* d32 = (unsigned*)&Bs[ch * 130 + seg * 8];
            const unsigned* s32 = (const unsigned*)&v;
            d32[0] = s32[0]; d32[1] = s32[1]; d32[2] = s32[2]; d32[3] = s32[3];
        }
    }
    __syncthreads();

    // gather B fragments: Bf[fb][ks][e] = Bs[(ks*32+lg*8+e)][px]
    bf16x8 Bf[4][6];
#pragma unroll
    for (int fb = 0; fb < 4; ++fb) {
        int px = wn * 64 + fb * 16 + li;
#pragma unroll
        for (int ks = 0; ks < 6; ++ks) {
            bf16x8 v;
#pragma unroll
            for (int e = 0; e < 8; ++e)
                v[e] = (short)Bs[(ks * 32 + lg * 8 + e) * 130 + px];
            Bf[fb][ks] = v;
        }
    }
    __syncthreads();   // all gathers done -> Bs region is dead, safe to overlay scratch

    float* Ls32 = (float*)Bs;          // epilogue scratch: per wave 16 rows * 68 words
    const int wbase = w * 1088;        // 4 waves * 4352 B = 17,408 B <= 49,920 B
    const int pxw = (int)px0 + wn * 64;
    const int Mtot = Mtiles * 64;
    const int r = lane >> 2, q = lane & 3;

    for (int mt = 0; mt < Mtiles; ++mt) {
        int oc0 = mt * 64;
        const unsigned short* ab = Aw + (long)(oc0 + wm * 32 + li) * 192 + lg * 8;
        f32x4 acc[2][4];
#pragma unroll
        for (int i = 0; i < 2; ++i)
#pragma unroll
            for (int j = 0; j < 4; ++j) acc[i][j] = (f32x4){0.f, 0.f, 0.f, 0.f};
#pragma unroll
        for (int ks = 0; ks < 6; ++ks) {
            bf16x8 a0 = *(const bf16x8*)(ab + ks * 32);
            bf16x8 a1 = *(const bf16x8*)(ab + 16 * 192 + ks * 32);
#pragma unroll
            for (int fb = 0; fb < 4; ++fb) {
                acc[0][fb] = __builtin_amdgcn_mfma_f32_16x16x32_bf16(a0, Bf[fb][ks], acc[0][fb], 0, 0, 0);
                acc[1][fb] = __builtin_amdgcn_mfma_f32_16x16x32_bf16(a1, Bf[fb][ks], acc[1][fb], 0, 0, 0);
            }
        }
        // LDS-bounce epilogue: scatter acc -> scratch, read packed, wide store.
#pragma unroll
        for (int fa = 0; fa < 2; ++fa) {
#pragma unroll
            for (int fb = 0; fb < 4; ++fb)
#pragma unroll
                for (int ii = 0; ii < 4; ++ii)
                    Ls32[wbase + (lg * 4 + ii) * 68 + fb * 16 + li] = acc[fa][fb][ii];
            f32x4 c0 = *(f32x4*)&Ls32[wbase + r * 68 + q * 16 + 0];
            f32x4 c1 = *(f32x4*)&Ls32[wbase + r * 68 + q * 16 + 4];
            f32x4 c2 = *(f32x4*)&Ls32[wbase + r * 68 + q * 16 + 8];
            f32x4 c3 = *(f32x4*)&Ls32[wbase + r * 68 + q * 16 + 12];
            int m = oc0 + wm * 32 + fa * 16 + r;
            long base = ((long)b * Mtot + m) * HW + pxw + q * 16;
            if (MODE == 1) {
                *(f32x4*)(outf + base + 0)  = c0;
                *(f32x4*)(outf + base + 4)  = c1;
                *(f32x4*)(outf + base + 8)  = c2;
                *(f32x4*)(outf + base + 12) = c3;
            } else {
                bf16x8 o0, o1;
#pragma unroll
                for (int e = 0; e < 4; ++e) {
                    o0[e]     = (short)f2b(c0[e]);
                    o0[e + 4] = (short)f2b(c1[e]);
                    o1[e]     = (short)f2b(c2[e]);
                    o1[e + 4] = (short)f2b(c3[e]);
                }
                *(bf16x8*)(outb + base)     = o0;
                *(bf16x8*)(outb + base + 8) = o1;
            }
        }
    }
}

// ---------------- depthwise 3x3 SAME v2: 32-row strips, aligned b64 LDS reads,
// 4x x 8y outputs/thread; q/k written directly in qkT layout, v planar.
__global__ __launch_bounds__(256) void dwconv2(const unsigned short* __restrict__ in,
                                               const float* __restrict__ wdw,
                                               unsigned short* __restrict__ qkT,
                                               unsigned short* __restrict__ vpl)
{
    __shared__ unsigned short Ls[34 * 272];
    int tid = threadIdx.x;
    int zp = blockIdx.y;
    int b = zp / 576, ch3 = zp % 576;
    int y0 = blockIdx.x * 32;
    const unsigned short* ip = in + (long)zp * HW;
    float w9[9];
#pragma unroll
    for (int t = 0; t < 9; ++t) w9[t] = wdw[ch3 * 9 + t];

    const bf16x8 z8 = (bf16x8){0, 0, 0, 0, 0, 0, 0, 0};
    if (tid < 34)               *(bf16x8*)&Ls[tid * 272] = z8;
    else if (tid < 68)          *(bf16x8*)&Ls[(tid - 34) * 272 + 264] = z8;
#pragma unroll
    for (int it = 0; it < 5; ++it) {
        int task = it * 256 + tid;
        if (task < 1088) {
            int r = task >> 5, seg = task & 31;
            int gy = y0 - 1 + r;
            bf16x8 v = z8;
            if (gy >= 0 && gy < 256) v = *(const bf16x8*)(ip + gy * 256 + seg * 8);
            *(bf16x8*)&Ls[r * 272 + 8 + seg * 8] = v;
        }
    }
    __syncthreads();

    int xg = tid & 63, yg = tid >> 6;
    int x0 = xg * 4;
    float acc[8][4];
#pragma unroll
    for (int yy = 0; yy < 8; ++yy)
#pragma unroll
        for (int xi = 0; xi < 4; ++xi) acc[yy][xi] = 0.f;

#pragma unroll
    for (int rr = 0; rr < 10; ++rr) {
        const unsigned short* lp = &Ls[(yg * 8 + rr) * 272 + 8 + x0];
        bf16x4 A  = *(const bf16x4*)(lp - 4);
        bf16x4 Bv = *(const bf16x4*)(lp);
        bf16x4 Cv = *(const bf16x4*)(lp + 4);
        float f[6] = { b2f((unsigned short)A[3]),  b2f((unsigned short)Bv[0]),
                       b2f((unsigned short)Bv[1]), b2f((unsigned short)Bv[2]),
                       b2f((unsigned short)Bv[3]), b2f((unsigned short)Cv[0]) };
#pragma unroll
        for (int dy = 0; dy < 3; ++dy) {
            int yy = rr - dy;
            if (yy >= 0 && yy < 8) {
#pragma unroll
                for (int dx = 0; dx < 3; ++dx)
#pragma unroll
                    for (int xi = 0; xi < 4; ++xi)
                        acc[yy][xi] = fmaf(w9[dy * 3 + dx], f[dx + xi], acc[yy][xi]);
            }
        }
    }

    if (ch3 < 384) {
        int isk = ch3 >= 192 ? 1 : 0;
        int chq = ch3 - isk * 192;
        int hh = chq / 48, cc = chq % 48;
        long zbase = (long)(b * 8 + isk * 4 + hh) * 3145728L + (long)cc * 256 + y0 + yg * 8;
#pragma unroll
        for (int xi = 0; xi < 4; ++xi) {
            bf16x8 pv;
#pragma unroll
            for (int yy = 0; yy < 8; ++yy) pv[yy] = (short)f2b(acc[yy][xi]);
            *(bf16x8*)(qkT + zbase + (long)(x0 + xi) * 12288) = pv;
        }
    } else {
        unsigned short* ob = vpl + (long)(b * 192 + ch3 - 384) * HW + (long)(y0 + yg * 8) * 256 + x0;
#pragma unroll
        for (int yy = 0; yy < 8; ++yy) {
            bf16x4 pv;
#pragma unroll
            for (int xi = 0; xi < 4; ++xi) pv[xi] = (short)f2b(acc[yy][xi]);
            *(bf16x4*)(ob + yy * 256) = pv;
        }
    }
}

// ---------------- column norms: 1/max(||row of qkT||,eps). grid (256, 16)
__global__ __launch_bounds__(256) void norms_k(const unsigned short* __restrict__ qkT, float* __restrict__ norms)
{
    int i = blockIdx.x, z = blockIdx.y;
    const unsigned short* p = qkT + ((long)z * 256 + i) * 12288 + threadIdx.x * 8;
    float s = 0.f;
#pragma unroll
    for (int it = 0; it < 6; ++it) {
        bf16x8 v = *(const bf16x8*)(p + it * 2048);
#pragma unroll
        for (int e = 0; e < 8; ++e) { float f = b2f((unsigned short)v[e]); s = fmaf(f, f, s); }
    }
    for (int off = 32; off > 0; off >>= 1) s += __shfl_down(s, off, 64);
    __shared__ float r4[4];
    if ((threadIdx.x & 63) == 0) r4[threadIdx.x >> 6] = s;
    __syncthreads();
    if (threadIdx.x == 0) {
        float t = r4[0] + r4[1] + r4[2] + r4[3];
        norms[z * 256 + i] = 1.0f / fmaxf(sqrtf(t), 1e-12f);
    }
}

// ---------------- attn: Sp[sk][bh][i][j] partial of Q^T K. grid (2,2,128), K-chunk 768.
__global__ __launch_bounds__(256) void attn_qk(const unsigned short* __restrict__ qkT, float* __restrict__ Sp)
{
    __shared__ unsigned short Qs[128 * 40];
    __shared__ unsigned short Ks[128 * 40];
    int tid = threadIdx.x;
    int z = blockIdx.z; int bh = z >> 4, sk = z & 15; int b = bh >> 2, h = bh & 3;
    const unsigned short* qT = qkT + (long)(b * 8 + h) * 3145728;
    const unsigned short* kT = qkT + (long)(b * 8 + 4 + h) * 3145728;
    int i0 = blockIdx.x * 128, j0 = blockIdx.y * 128;
    int w = tid >> 6, lane = tid & 63, lg = lane >> 4, li = lane & 15;
    int wm = w >> 1, wn = w & 1;
    int srow = tid >> 2, sseg = (tid & 3) * 8;
    long qoff = (long)(i0 + srow) * 12288 + sk * 768 + sseg;
    long koff = (long)(j0 + srow) * 12288 + sk * 768 + sseg;

    f32x4 acc[4][4];
#pragma unroll
    for (int i = 0; i < 4; ++i)
#pragma unroll
        for (int j = 0; j < 4; ++j) acc[i][j] = (f32x4){0.f, 0.f, 0.f, 0.f};

    bf16x8 qr0 = *(const bf16x8*)(qT + qoff);
    bf16x8 qr1 = *(const bf16x8*)(qT + qoff + (long)64 * 12288);
    bf16x8 kr0 = *(const bf16x8*)(kT + koff);
    bf16x8 kr1 = *(const bf16x8*)(kT + koff + (long)64 * 12288);

#pragma unroll 1
    for (int ks = 0; ks < 24; ++ks) {
        *(bf16x8*)&Qs[srow * 40 + sseg] = qr0;
        *(bf16x8*)&Qs[(64 + srow) * 40 + sseg] = qr1;
        *(bf16x8*)&Ks[srow * 40 + sseg] = kr0;
        *(bf16x8*)&Ks[(64 + srow) * 40 + sseg] = kr1;
        if (ks < 23) {
            long o = (long)(ks + 1) * 32;
            qr0 = *(const bf16x8*)(qT + qoff + o);
            qr1 = *(const bf16x8*)(qT + qoff + (long)64 * 12288 + o);
            kr0 = *(const bf16x8*)(kT + koff + o);
            kr1 = *(const bf16x8*)(kT + koff + (long)64 * 12288 + o);
        }
        __syncthreads();
        bf16x8 af[4], bfr[4];
#pragma unroll
        for (int fa = 0; fa < 4; ++fa)
            af[fa] = *(const bf16x8*)&Qs[(wm * 64 + fa * 16 + li) * 40 + lg * 8];
#pragma unroll
        for (int fb = 0; fb < 4; ++fb)
            bfr[fb] = *(const bf16x8*)&Ks[(wn * 64 + fb * 16 + li) * 40 + lg * 8];
#pragma unroll
        for (int fa = 0; fa < 4; ++fa)
#pragma unroll
            for (int fb = 0; fb < 4; ++fb)
                acc[fa][fb] = __builtin_amdgcn_mfma_f32_16x16x32_bf16(af[fa], bfr[fb], acc[fa][fb], 0, 0, 0);
        __syncthreads();
    }

    float* op = Sp + ((long)(sk * 8 + bh) << 16);
#pragma unroll
    for (int fa = 0; fa < 4; ++fa) {
        int i = i0 + wm * 64 + fa * 16 + lg * 4;
#pragma unroll
        for (int fb = 0; fb < 4; ++fb) {
            int j = j0 + wn * 64 + fb * 16 + li;
#pragma unroll
            for (int ii = 0; ii < 4; ++ii)
                op[(long)(i + ii) * 256 + j] = acc[fa][fb][ii];
        }
    }
}

// ---------------- softmax over i with scaling; writes Pt in vattn B-fragment layout.
__global__ __launch_bounds__(256) void softmax_k(const float* __restrict__ Sp, const float* __restrict__ norms,
                                                 const float* __restrict__ temp, unsigned short* __restrict__ Pt)
{
    __shared__ float Sd[256 * 9];
    __shared__ float red[32 * 9];
    int tid = threadIdx.x;
    int g = blockIdx.x; int bh = g >> 5, jq = g & 31; int b = bh >> 2, h = bh & 3;
    int jl = tid & 7, iq = tid >> 3;
    int j = jq * 8 + jl;
    const float* nq = norms + (b * 8 + h) * 256;
    float invkj = norms[(b * 8 + 4 + h) * 256 + j] * temp[h];
    const float* sp = Sp + (long)bh * HW + j;

    float m = -1e30f;
#pragma unroll
    for (int ii = 0; ii < 8; ++ii) {
        int i = iq * 8 + ii;
        float s = 0.f;
#pragma unroll
        for (int sk = 0; sk < 16; ++sk) s += sp[((long)(sk * 8) << 16) + i * 256];
        float v = s * nq[i] * invkj;
        Sd[i * 9 + jl] = v;
        m = fmaxf(m, v);
    }
    red[iq * 9 + jl] = m;
    __syncthreads();
    m = -1e30f;
#pragma unroll
    for (int s2 = 0; s2 < 32; ++s2) m = fmaxf(m, red[s2 * 9 + jl]);
    __syncthreads();
    float sum = 0.f;
#pragma unroll
    for (int ii = 0; ii < 8; ++ii) sum += __expf(Sd[(iq * 8 + ii) * 9 + jl] - m);
    red[iq * 9 + jl] = sum;
    __syncthreads();
    sum = 0.f;
#pragma unroll
    for (int s2 = 0; s2 < 32; ++s2) sum += red[s2 * 9 + jl];
    float rs = 1.0f / sum;

    int fb = jq >> 1, li2 = (jq & 1) * 8 + jl;
    int ks = iq >> 2, lg = iq & 3;
    unsigned short* pt = Pt + (long)bh * HW + (long)((fb * 8 + ks) * 64 + lg * 16 + li2) * 8;
    bf16x8 pv;
#pragma unroll
    for (int ii = 0; ii < 8; ++ii)
        pv[ii] = (short)f2b(__expf(Sd[(iq * 8 + ii) * 9 + jl] - m) * rs);
    *(bf16x8*)pt = pv;
}

// ---------------- vattn: P in fragment layout (coalesced 1KB loads), no LDS. grid (192, 8)
__global__ __launch_bounds__(256) void vattn(const unsigned short* __restrict__ vpl,
                                             const unsigned short* __restrict__ Pt,
                                             unsigned short* __restrict__ vout)
{
    int tid = threadIdx.x;
    int w = tid >> 6, lane = tid & 63, lg = lane >> 4, li = lane & 15;
    int wm = w >> 1, wn = w & 1;
    int m0 = blockIdx.x * 64 + wm * 32;
    int bh = blockIdx.y; int b = bh >> 2, h = bh & 3;
    const unsigned short* V = vpl + (long)(b * 192 + h * 48) * HW;
    const unsigned short* P = Pt + (long)bh * HW + wn * 32768 + lane * 8;

    f32x4 acc[2][8];
#pragma unroll
    for (int i = 0; i < 2; ++i)
#pragma unroll
        for (int j = 0; j < 8; ++j) acc[i][j] = (f32x4){0.f, 0.f, 0.f, 0.f};

#pragma unroll 2
    for (int ks = 0; ks < 8; ++ks) {
        bf16x8 a0 = *(const bf16x8*)(V + (long)(m0 + li) * 256 + ks * 32 + lg * 8);
        bf16x8 a1 = *(const bf16x8*)(V + (long)(m0 + 16 + li) * 256 + ks * 32 + lg * 8);
#pragma unroll
        for (int fb2 = 0; fb2 < 8; ++fb2) {
            bf16x8 bb = *(const bf16x8*)(P + (fb2 * 8 + ks) * 512);
            acc[0][fb2] = __builtin_amdgcn_mfma_f32_16x16x32_bf16(a0, bb, acc[0][fb2], 0, 0, 0);
            acc[1][fb2] = __builtin_amdgcn_mfma_f32_16x16x32_bf16(a1, bb, acc[1][fb2], 0, 0, 0);
        }
    }
    unsigned short* ob = vout + (long)(b * 192 + h * 48) * HW;
#pragma unroll
    for (int fa = 0; fa < 2; ++fa) {
#pragma unroll
        for (int fb2 = 0; fb2 < 8; ++fb2) {
            int j = (wn * 8 + fb2) * 16 + li;
#pragma unroll
            for (int ii = 0; ii < 4; ++ii) {
                int m = m0 + fa * 16 + lg * 4 + ii;
                ob[((long)(m >> 8) << 16) + ((m & 255) << 8) + j] = f2b(acc[fa][fb2][ii]);
            }
        }
    }
}

extern "C" void kernel_launch(void* const* d_in, const int* in_sizes, int n_in,
                              void* d_out, int out_size, void* d_ws, size_t ws_size,
                              hipStream_t stream)
{
    (void)in_sizes; (void)n_in; (void)out_size; (void)ws_size;
    const float* x      = (const float*)d_in[0];
    const float* w_qkv  = (const float*)d_in[1];
    const float* w_dw   = (const float*)d_in[2];
    const float* w_proj = (const float*)d_in[3];
    const float* temp   = (const float*)d_in[4];
    float* out = (float*)d_out;
    char* ws = (char*)d_ws;

    unsigned short* qkv_pre = (unsigned short*)(ws + OFF_A0);
    float*          Sp      = (float*)(ws + OFF_SP);
    unsigned short* vout    = (unsigned short*)(ws + OFF_A0);
    unsigned short* qkT     = (unsigned short*)(ws + OFF_QKT);
    unsigned short* vpl     = (unsigned short*)(ws + OFF_VPL);
    unsigned short* Pt      = (unsigned short*)(ws + OFF_PT);
    float*          norms   = (float*)(ws + OFF_NORMS);
    unsigned short* wqb     = (unsigned short*)(ws + OFF_WQ);
    unsigned short* wpb     = (unsigned short*)(ws + OFF_WP);

    conv_w<<<64, 256, 0, stream>>>(w_qkv, w_proj, wqb, wpb);
    gemm_pm5<0><<<1024, 256, 0, stream>>>(wqb, (const void*)x, qkv_pre, nullptr, 9);
    dwconv2<<<dim3(8, 1152), 256, 0, stream>>>(qkv_pre, w_dw, qkT, vpl);
    norms_k<<<dim3(256, 16), 256, 0, stream>>>(qkT, norms);
    attn_qk<<<dim3(2, 2, 128), 256, 0, stream>>>(qkT, Sp);
    softmax_k<<<256, 256, 0, stream>>>(Sp, norms, temp, Pt);
    vattn<<<dim3(192, 8), 256, 0, stream>>>(vpl, Pt, vout);
    gemm_pm5<1><<<1024, 256, 0, stream>>>(wpb, (const void*)vout, nullptr, out, 3);
}